// Round 2
// baseline (6985.290 us; speedup 1.0000x reference)
//
#include <hip/hip_runtime.h>

#define T_ 2048
#define B_ 128
#define IN_ 64
#define H_ 128
#define OUT_ 32
#define BS_ 16      // batch per block
#define NBLK_ (B_ / BS_)

typedef _Float16 half8 __attribute__((ext_vector_type(8)));
typedef _Float16 half4v __attribute__((ext_vector_type(4)));
typedef _Float16 half2v __attribute__((ext_vector_type(2)));
typedef float float4v __attribute__((ext_vector_type(4)));

// LDS layout (bytes)
#define WIH0A_OFF 0        // 64 blocks (mt 0..31, kt 0..1) x 1024B A-frags
#define FCA_OFF   65536    // 8 blocks (mt 0..1, kt 0..3) x 1024B
#define XB_OFF    73728    // x(t) f16, col n stride 272, k*2
#define H0B_OFF   78080    // 2 x 4352 (p)
#define H1B_OFF   86784    // 2 x 4352 (q)
#define SM_BYTES  95488
#define CSTR 272           // column stride bytes (68 words -> <=2-way banks)

__device__ __forceinline__ float sigm(float x) { return 1.0f / (1.0f + __expf(-x)); }
__device__ __forceinline__ float tanh_f(float x) { return 1.0f - 2.0f / (1.0f + __expf(2.0f * x)); }

// build A-fragment for 16x16x32 f16: lane holds A[m=lane&15][k=quad*8+j]
__device__ __forceinline__ half8 make_afrag(const float* __restrict__ W, int K, int row, int col) {
  const float* p = W + (size_t)row * K + col;
  float4 a = *(const float4*)(p);
  float4 b = *(const float4*)(p + 4);
  half8 h;
  h[0] = (_Float16)a.x; h[1] = (_Float16)a.y; h[2] = (_Float16)a.z; h[3] = (_Float16)a.w;
  h[4] = (_Float16)b.x; h[5] = (_Float16)b.y; h[6] = (_Float16)b.z; h[7] = (_Float16)b.w;
  return h;
}

__global__ __launch_bounds__(512, 2) void lstm_mfma(
    const float* __restrict__ x, const float* __restrict__ w_ih0,
    const float* __restrict__ w_hh0, const float* __restrict__ w_ih1,
    const float* __restrict__ w_hh1, const float* __restrict__ fc_w,
    const float* __restrict__ fc_b, float* __restrict__ out)
{
  extern __shared__ char sm[];
  const int tid  = threadIdx.x;
  const int lane = tid & 63;
  const int w    = tid >> 6;      // wave 0..7 = H-tile index
  const int quad = lane >> 4;     // 0..3
  const int n    = lane & 15;     // batch col within tile / m-row for A
  const int bb   = blockIdx.x * BS_;

  // ---- resident A-fragments: w_hh0, w_ih1, w_hh1 (4 gates x 4 ktiles each) ----
  half8 a_hh0[4][4], a_ih1[4][4], a_hh1[4][4];
#pragma unroll
  for (int g = 0; g < 4; ++g) {
    const int row = g * H_ + w * 16 + n;
#pragma unroll
    for (int kt = 0; kt < 4; ++kt) {
      const int col = kt * 32 + quad * 8;
      a_hh0[g][kt] = make_afrag(w_hh0, H_, row, col);
      a_ih1[g][kt] = make_afrag(w_ih1, H_, row, col);
      a_hh1[g][kt] = make_afrag(w_hh1, H_, row, col);
    }
  }
  // ---- w_ih0 A-frags -> LDS (wave-private blocks) ----
#pragma unroll
  for (int g = 0; g < 4; ++g) {
    const int row = g * H_ + w * 16 + n;
#pragma unroll
    for (int kt = 0; kt < 2; ++kt) {
      half8 h = make_afrag(w_ih0, IN_, row, kt * 32 + quad * 8);
      *(half8*)(sm + WIH0A_OFF + (size_t)(((g * 8 + w) * 2 + kt) * 1024 + lane * 16)) = h;
    }
  }
  // ---- fc_w A-frags -> LDS (waves 0,1) ----
  float4 fb = make_float4(0.f, 0.f, 0.f, 0.f);
  if (w < 2) {
#pragma unroll
    for (int kt = 0; kt < 4; ++kt) {
      half8 h = make_afrag(fc_w, H_, w * 16 + n, kt * 32 + quad * 8);
      *(half8*)(sm + FCA_OFF + (size_t)((w * 4 + kt) * 1024 + lane * 16)) = h;
    }
    fb = *(const float4*)(fc_b + w * 16 + quad * 4);
  }
  // ---- zero h buffers [0], stage x(0) ----
  for (int i = tid; i < 4352 / 4; i += 512) {
    ((unsigned*)(sm + H0B_OFF))[i] = 0u;
    ((unsigned*)(sm + H1B_OFF))[i] = 0u;
  }
  {
    const int bl = tid >> 5, kk = (tid & 31) * 2;
    float2 xv = *(const float2*)(x + ((size_t)0 * B_ + bb + bl) * IN_ + kk);
    half2v xh; xh[0] = (_Float16)xv.x; xh[1] = (_Float16)xv.y;
    *(half2v*)(sm + XB_OFF + bl * CSTR + kk * 2) = xh;
  }
  __syncthreads();

  float4v c0 = {0.f, 0.f, 0.f, 0.f};
  float4v c1 = {0.f, 0.f, 0.f, 0.f};
  int p = 0, q = 0;
  const size_t base_hn = (size_t)T_ * B_ * OUT_;

#pragma unroll 1
  for (int t = 0; t < T_; ++t) {
    // prefetch x(t+1) into regs (consumed in phase B)
    float2 xv;
    const bool havex = (t + 1 < T_);
    const int bl = tid >> 5, kk = (tid & 31) * 2;
    if (havex) xv = *(const float2*)(x + ((size_t)(t + 1) * B_ + bb + bl) * IN_ + kk);

    // ---- FC(t-1): waves 0,1 ----
    if (w < 2 && t > 0) {
      float4v accF = {0.f, 0.f, 0.f, 0.f};
#pragma unroll
      for (int kt = 0; kt < 4; ++kt) {
        half8 Bv = *(const half8*)(sm + H1B_OFF + q * 4352 + n * CSTR + (kt * 32 + quad * 8) * 2);
        half8 Av = *(const half8*)(sm + FCA_OFF + (w * 4 + kt) * 1024 + lane * 16);
        accF = __builtin_amdgcn_mfma_f32_16x16x32_f16(Av, Bv, accF, 0, 0, 0);
      }
      float* op = out + ((size_t)(t - 1) * B_ + bb + n) * OUT_ + w * 16 + quad * 4;
      *(float4*)op = make_float4(accF[0] + fb.x, accF[1] + fb.y, accF[2] + fb.z, accF[3] + fb.w);
    }

    // ---- phase A: layer 0 gates ----
    {
      float4v acc[4] = {{0.f,0.f,0.f,0.f},{0.f,0.f,0.f,0.f},{0.f,0.f,0.f,0.f},{0.f,0.f,0.f,0.f}};
#pragma unroll
      for (int kt = 0; kt < 2; ++kt) {
        half8 Bv = *(const half8*)(sm + XB_OFF + n * CSTR + (kt * 32 + quad * 8) * 2);
#pragma unroll
        for (int g = 0; g < 4; ++g) {
          half8 Av = *(const half8*)(sm + WIH0A_OFF + (((g * 8 + w) * 2 + kt) * 1024 + lane * 16));
          acc[g] = __builtin_amdgcn_mfma_f32_16x16x32_f16(Av, Bv, acc[g], 0, 0, 0);
        }
      }
#pragma unroll
      for (int kt = 0; kt < 4; ++kt) {
        half8 Bv = *(const half8*)(sm + H0B_OFF + p * 4352 + n * CSTR + (kt * 32 + quad * 8) * 2);
#pragma unroll
        for (int g = 0; g < 4; ++g)
          acc[g] = __builtin_amdgcn_mfma_f32_16x16x32_f16(a_hh0[g][kt], Bv, acc[g], 0, 0, 0);
      }
      half4v hh;
#pragma unroll
      for (int r = 0; r < 4; ++r) {
        float iv = sigm(acc[0][r]), fv = sigm(acc[1][r]);
        float gv = tanh_f(acc[2][r]), ov = sigm(acc[3][r]);
        c0[r] = fv * c0[r] + iv * gv;
        hh[r] = (_Float16)(ov * tanh_f(c0[r]));
      }
      *(half4v*)(sm + H0B_OFF + (1 - p) * 4352 + n * CSTR + (w * 16 + quad * 4) * 2) = hh;
    }
    __syncthreads();

    // ---- phase B: stage x(t+1), layer 1 gates ----
    if (havex) {
      half2v xh; xh[0] = (_Float16)xv.x; xh[1] = (_Float16)xv.y;
      *(half2v*)(sm + XB_OFF + bl * CSTR + kk * 2) = xh;
    }
    {
      float4v acc[4] = {{0.f,0.f,0.f,0.f},{0.f,0.f,0.f,0.f},{0.f,0.f,0.f,0.f},{0.f,0.f,0.f,0.f}};
#pragma unroll
      for (int kt = 0; kt < 4; ++kt) {
        half8 Bv = *(const half8*)(sm + H0B_OFF + (1 - p) * 4352 + n * CSTR + (kt * 32 + quad * 8) * 2);
#pragma unroll
        for (int g = 0; g < 4; ++g)
          acc[g] = __builtin_amdgcn_mfma_f32_16x16x32_f16(a_ih1[g][kt], Bv, acc[g], 0, 0, 0);
      }
#pragma unroll
      for (int kt = 0; kt < 4; ++kt) {
        half8 Bv = *(const half8*)(sm + H1B_OFF + q * 4352 + n * CSTR + (kt * 32 + quad * 8) * 2);
#pragma unroll
        for (int g = 0; g < 4; ++g)
          acc[g] = __builtin_amdgcn_mfma_f32_16x16x32_f16(a_hh1[g][kt], Bv, acc[g], 0, 0, 0);
      }
      half4v hh;
#pragma unroll
      for (int r = 0; r < 4; ++r) {
        float iv = sigm(acc[0][r]), fv = sigm(acc[1][r]);
        float gv = tanh_f(acc[2][r]), ov = sigm(acc[3][r]);
        c1[r] = fv * c1[r] + iv * gv;
        hh[r] = (_Float16)(ov * tanh_f(c1[r]));
      }
      *(half4v*)(sm + H1B_OFF + (1 - q) * 4352 + n * CSTR + (w * 16 + quad * 4) * 2) = hh;
    }
    __syncthreads();
    p ^= 1; q ^= 1;
  }

  // ---- final FC for t = T-1 (h1buf[q] holds h1(T-1)) ----
  if (w < 2) {
    float4v accF = {0.f, 0.f, 0.f, 0.f};
#pragma unroll
    for (int kt = 0; kt < 4; ++kt) {
      half8 Bv = *(const half8*)(sm + H1B_OFF + q * 4352 + n * CSTR + (kt * 32 + quad * 8) * 2);
      half8 Av = *(const half8*)(sm + FCA_OFF + (w * 4 + kt) * 1024 + lane * 16);
      accF = __builtin_amdgcn_mfma_f32_16x16x32_f16(Av, Bv, accF, 0, 0, 0);
    }
    float* op = out + ((size_t)(T_ - 1) * B_ + bb + n) * OUT_ + w * 16 + quad * 4;
    *(float4*)op = make_float4(accF[0] + fb.x, accF[1] + fb.y, accF[2] + fb.z, accF[3] + fb.w);
  }

  // ---- h_n / c_n ----
  {
    float* hn = out + base_hn;
    float* cn = hn + 2 * B_ * H_;
    const int hoff = w * 16 + quad * 4;
    half4v h0f = *(const half4v*)(sm + H0B_OFF + p * 4352 + n * CSTR + hoff * 2);
    half4v h1f = *(const half4v*)(sm + H1B_OFF + q * 4352 + n * CSTR + hoff * 2);
    *(float4*)(hn + ((size_t)(bb + n)) * H_ + hoff) =
        make_float4((float)h0f[0], (float)h0f[1], (float)h0f[2], (float)h0f[3]);
    *(float4*)(hn + ((size_t)(B_ + bb + n)) * H_ + hoff) =
        make_float4((float)h1f[0], (float)h1f[1], (float)h1f[2], (float)h1f[3]);
    *(float4*)(cn + ((size_t)(bb + n)) * H_ + hoff) = make_float4(c0[0], c0[1], c0[2], c0[3]);
    *(float4*)(cn + ((size_t)(B_ + bb + n)) * H_ + hoff) = make_float4(c1[0], c1[1], c1[2], c1[3]);
  }
}

extern "C" void kernel_launch(void* const* d_in, const int* in_sizes, int n_in,
                              void* d_out, int out_size, void* d_ws, size_t ws_size,
                              hipStream_t stream) {
  const float* x     = (const float*)d_in[0];
  const float* w_ih0 = (const float*)d_in[1];
  const float* w_hh0 = (const float*)d_in[2];
  const float* w_ih1 = (const float*)d_in[3];
  const float* w_hh1 = (const float*)d_in[4];
  const float* fc_w  = (const float*)d_in[5];
  const float* fc_b  = (const float*)d_in[6];
  // raise dynamic-LDS cap (host-side, idempotent, not a stream op -> capture-safe)
  hipFuncSetAttribute((const void*)lstm_mfma,
                      hipFuncAttributeMaxDynamicSharedMemorySize, SM_BYTES);
  lstm_mfma<<<NBLK_, 512, SM_BYTES, stream>>>(x, w_ih0, w_hh0, w_ih1, w_hh1,
                                              fc_w, fc_b, (float*)d_out);
}